// Round 9
// baseline (215.472 us; speedup 1.0000x reference)
//
#include <hip/hip_runtime.h>
#include <hip/hip_bf16.h>

// Problem constants
#define NB 16
#define DD 64
#define HW 4096          // 64*64
#define NTOT 65536       // NB*HW
#define KC 1024

// Output chunk offsets (FLOAT32 elements, return order)
#define O_EK   0                         // e_k_ste [16,64,64,64] = 4194304
#define O_IDX  4194304                   // indices [16,64,64]    = 65536
#define O_L    4259840                   // L_commit scalar       = 1
#define O_CB   4259841                   // new_codebook [1024,64]= 65536
#define O_CNT  4325377                   // new_count [1024]      = 1024
#define O_SUM  4326401                   // new_sum [1024,64]     = 65536

// Workspace layout (float element offsets) — ~1.34 MB total
#define WS_IDX    0          // [0, 65536) int32
#define WS_LCPART 65536      // 512 floats
#define WS_N      66048      // scalar
#define WS_CNORM  66560      // 1024 (16B-aligned)
#define WS_PSUM   67584      // 4 x 65536 = 262144 -> ends 329728
#define WS_PCNT   329728     // 4 x 1024 ints -> ends 333824

// cnorm (16-lane slice per code) + n = 0.99*sum(ema_count) + 0.01*N
__global__ __launch_bounds__(256) void k_pre(const float* __restrict__ cb,
                                             const float* __restrict__ ema_count,
                                             float* __restrict__ cnorm,
                                             float* __restrict__ n_ws) {
    const int t = threadIdx.x;
    const int w = (blockIdx.x * 256 + t) >> 6;   // code 0..1023 (grid 256)
    const int l = t & 63;
    float s = 0.f;
    if (l < 16) {
        float4 v = *(const float4*)(cb + (size_t)w * DD + l * 4);
        s = v.x * v.x + v.y * v.y + v.z * v.z + v.w * v.w;
    }
#pragma unroll
    for (int m = 1; m <= 8; m <<= 1) s += __shfl_xor(s, m, 64);
    if (l == 0) cnorm[w] = s;

    if (blockIdx.x == 0) {
        __shared__ float red[256];
        red[t] = ema_count[t] + ema_count[t + 256] + ema_count[t + 512] + ema_count[t + 768];
        __syncthreads();
        for (int s2 = 128; s2 >= 1; s2 >>= 1) {
            if (t < s2) red[t] += red[t + s2];
            __syncthreads();
        }
        if (t == 0) n_ws[0] = 0.99f * red[0] + 0.01f * 65536.0f;
    }
}

// Fused: distance GEMM (8x8 tile, split columns) + argmin + e_k_ste/index + L_commit partial.
__global__ __launch_bounds__(256) void k_main(const float* __restrict__ z_e,
                                              const float* __restrict__ cb,
                                              const float* __restrict__ cnorm,
                                              float* __restrict__ out,
                                              int* __restrict__ idx_ws,
                                              float* __restrict__ lc_part) {
    __shared__ __align__(16) float At[64 * 128];   // z tile [j][i], live whole kernel (32 KB)
    __shared__ __align__(16) float Bt[64 * 128];   // codebook tile [j][k] (32 KB); reduce scratch
    __shared__ __align__(16) float cn_lds[KC];     // 4 KB
    __shared__ float zn[128];
    __shared__ int   idx_lds[128];
    __shared__ float lcred[4];

    const int t  = threadIdx.x;
    const int tx = t & 15;
    const int ty = t >> 4;
    const int n0 = blockIdx.x * 128;       // 512 blocks
    const int b   = n0 >> 12;
    const int hw0 = n0 & 4095;
    const float* zbase = z_e + (size_t)b * (DD * HW) + hw0;

    // ---- Load A tile (coalesced along hw) + cnorm to LDS ----
#pragma unroll
    for (int s = 0; s < 8; ++s) {
        int idx = t + s * 256;              // 0..2047 float4s
        int j   = idx >> 5;
        int i4  = (idx & 31) << 2;
        float4 v = *(const float4*)(zbase + (size_t)j * HW + i4);
        *(float4*)(&At[j * 128 + i4]) = v;
    }
    *(float4*)(&cn_lds[t * 4]) = *(const float4*)(cnorm + t * 4);
    __syncthreads();

    if (t < 128) {
        float s = 0.f;
        for (int j = 0; j < 64; ++j) { float a = At[j * 128 + t]; s = fmaf(a, a, s); }
        zn[t] = s;
    }
    __syncthreads();

    const int row0 = ty * 8;
    const int colA = tx * 4;        // columns [colA, colA+4)
    const int colB = 64 + tx * 4;   // columns [colB, colB+4)  (2-way LDS access, free)
    float znr[8];
#pragma unroll
    for (int r = 0; r < 8; ++r) znr[r] = zn[row0 + r];

    float mv[8]; int mi[8];
#pragma unroll
    for (int r = 0; r < 8; ++r) { mv[r] = 3.4e38f; mi[r] = 0; }

    for (int kt = 0; kt < 8; ++kt) {
        const int k0 = kt * 128;
        __syncthreads();                    // protect Bt from previous readers
        // Staging: kk lane-consecutive -> LDS stores conflict-free; global reads
        // stride-256B per lane but cb is 256 KB, L2-hot.
#pragma unroll
        for (int s = 0; s < 8; ++s) {
            int idx = t + s * 256;          // 0..2047
            int kk  = idx & 127;
            int jq  = (idx >> 7) << 2;      // 0,4,...,60
            float4 v = *(const float4*)(cb + (size_t)(k0 + kk) * DD + jq);
            Bt[(jq + 0) * 128 + kk] = v.x;
            Bt[(jq + 1) * 128 + kk] = v.y;
            Bt[(jq + 2) * 128 + kk] = v.z;
            Bt[(jq + 3) * 128 + kk] = v.w;
        }
        __syncthreads();

        float acc[8][8];
#pragma unroll
        for (int r = 0; r < 8; ++r)
#pragma unroll
            for (int c = 0; c < 8; ++c) acc[r][c] = 0.f;

#pragma unroll 8
        for (int j = 0; j < 64; ++j) {
            float4 a0 = *(const float4*)(&At[j * 128 + row0]);
            float4 a1 = *(const float4*)(&At[j * 128 + row0 + 4]);
            float4 b0 = *(const float4*)(&Bt[j * 128 + colA]);
            float4 b1 = *(const float4*)(&Bt[j * 128 + colB]);
            float ar[8] = {a0.x, a0.y, a0.z, a0.w, a1.x, a1.y, a1.z, a1.w};
            float bc[8] = {b0.x, b0.y, b0.z, b0.w, b1.x, b1.y, b1.z, b1.w};
#pragma unroll
            for (int r = 0; r < 8; ++r)
#pragma unroll
                for (int c = 0; c < 8; ++c)
                    acc[r][c] = fmaf(ar[r], bc[c], acc[r][c]);
        }

        // candidate code order within thread: colA+0..3 then colB+0..3 — ascending,
        // and ascending across k-tiles -> strict < keeps first occurrence (np.argmin)
#pragma unroll
        for (int c = 0; c < 8; ++c) {
            int   kg = k0 + ((c < 4) ? (colA + c) : (colB + c - 4));
            float cn = cn_lds[kg];
#pragma unroll
            for (int r = 0; r < 8; ++r) {
                float v = (znr[r] - 2.0f * acc[r][c]) + cn;
                if (v < mv[r]) { mv[r] = v; mi[r] = kg; }
            }
        }
    }

    // ---- Argmin reduction in Bt scratch (At stays intact) ----
    __syncthreads();
    float* rv = Bt;                       // [128][17] floats = 2176
    int*   ri = (int*)(Bt + 2176);        // [128][17] ints   = 2176 (Bt has 8192)
#pragma unroll
    for (int r = 0; r < 8; ++r) {
        rv[(row0 + r) * 17 + tx] = mv[r];
        ri[(row0 + r) * 17 + tx] = mi[r];
    }
    __syncthreads();
    if (t < 128) {
        float best = rv[t * 17 + 0];
        int   bi   = ri[t * 17 + 0];
#pragma unroll
        for (int c = 1; c < 16; ++c) {
            float v = rv[t * 17 + c];
            int   i = ri[t * 17 + c];
            if (v < best || (v == best && i < bi)) { best = v; bi = i; }
        }
        if ((unsigned)bi > 1023u) bi = 0;
        idx_lds[t] = bi;
        out[O_IDX + n0 + t] = (float)bi;
        idx_ws[n0 + t] = bi;
    }
    __syncthreads();

    // ---- e_k_ste + L_commit from LDS tile ----
    const int r   = t >> 1;
    const int j0  = (t & 1) * 32;
    int k = idx_lds[r];
    const float* ck = cb + (size_t)k * DD;
    const size_t obase = (size_t)b * (DD * HW) + (size_t)(hw0 + r);

    float lc = 0.f;
#pragma unroll 8
    for (int j = j0; j < j0 + 32; ++j) {
        float z = At[j * 128 + r];
        float e = ck[j];
        out[O_EK + obase + (size_t)j * HW] = z + (e - z);
        float d = z - e;
        lc = fmaf(d, d, lc);
    }
#pragma unroll
    for (int m = 32; m >= 1; m >>= 1) lc += __shfl_xor(lc, m, 64);
    if ((t & 63) == 0) lcred[t >> 6] = lc;
    __syncthreads();
    if (t == 0) lc_part[blockIdx.x] = lcred[0] + lcred[1] + lcred[2] + lcred[3];
}

// 256 blocks: (j, chunk c). Vectorized loads; LDS accumulate; j==0 also histograms.
__global__ __launch_bounds__(1024) void k_sums(const int* __restrict__ idx_ws,
                                               const float* __restrict__ z_e,
                                               float* __restrict__ psum,
                                               int* __restrict__ pcnt) {
    __shared__ float acc[KC];
    __shared__ int bins[KC];
    const int j = blockIdx.x & 63;
    const int c = blockIdx.x >> 6;     // 0..3
    const int t = threadIdx.x;
    acc[t] = 0.f;
    bins[t] = 0;
    __syncthreads();
    const float* zj = z_e + (size_t)j * HW;
    const int base = c * 16384;
    if (j == 0) {
#pragma unroll
        for (int i = 0; i < 4; ++i) {
            int n4 = base + i * 4096 + t * 4;
            int b = n4 >> 12, hw = n4 & 4095;
            float4 z4 = *(const float4*)(zj + (size_t)b * (DD * HW) + hw);
            int4   k4 = *(const int4*)(idx_ws + n4);
            atomicAdd(&acc[k4.x], z4.x); atomicAdd(&bins[k4.x], 1);
            atomicAdd(&acc[k4.y], z4.y); atomicAdd(&bins[k4.y], 1);
            atomicAdd(&acc[k4.z], z4.z); atomicAdd(&bins[k4.z], 1);
            atomicAdd(&acc[k4.w], z4.w); atomicAdd(&bins[k4.w], 1);
        }
    } else {
#pragma unroll
        for (int i = 0; i < 4; ++i) {
            int n4 = base + i * 4096 + t * 4;
            int b = n4 >> 12, hw = n4 & 4095;
            float4 z4 = *(const float4*)(zj + (size_t)b * (DD * HW) + hw);
            int4   k4 = *(const int4*)(idx_ws + n4);
            atomicAdd(&acc[k4.x], z4.x);
            atomicAdd(&acc[k4.y], z4.y);
            atomicAdd(&acc[k4.z], z4.z);
            atomicAdd(&acc[k4.w], z4.w);
        }
    }
    __syncthreads();
    psum[(size_t)c * 65536 + j * 1024 + t] = acc[t];
    if (j == 0) pcnt[c * 1024 + t] = bins[t];
}

// Fused epilogue, coalesced on outputs: e = k*64+j. 64 blocks x 1024.
__global__ __launch_bounds__(1024) void k_epi(const float* __restrict__ psum,
                                              const int* __restrict__ pcnt,
                                              const float* __restrict__ ema_sum,
                                              const float* __restrict__ ema_count,
                                              const float* __restrict__ n_ws,
                                              const float* __restrict__ lc_part,
                                              float* __restrict__ out) {
    const int t = threadIdx.x;
    const int e = blockIdx.x * 1024 + t;   // 0..65535
    const int k = e >> 6, j = e & 63;
    // psum layout [c][j][k] -> scattered reads, 1 MB L2-hot
    float s4 = psum[j * 1024 + k] + psum[65536 + j * 1024 + k]
             + psum[131072 + j * 1024 + k] + psum[196608 + j * 1024 + k];
    float ns = ema_sum[e] * 0.99f + 0.01f * s4;              // coalesced
    out[O_SUM + e] = ns;                                     // coalesced
    int cnt = pcnt[k] + pcnt[1024 + k] + pcnt[2048 + k] + pcnt[3072 + k];
    float nc = ema_count[k] * 0.99f + 0.01f * (float)cnt;
    float n  = n_ws[0];
    float cs = (nc + 1e-5f) / (n + 1024.0f * 1e-5f) * n;
    out[O_CB + e] = ns / cs;                                 // coalesced
    if (blockIdx.x == 0) {
        // t indexes codes directly here
        int c2 = pcnt[t] + pcnt[1024 + t] + pcnt[2048 + t] + pcnt[3072 + t];
        out[O_CNT + t] = ema_count[t] * 0.99f + 0.01f * (float)c2;
    }
    if (blockIdx.x == 1) {
        __shared__ float red[512];
        if (t < 512) red[t] = lc_part[t];
        __syncthreads();
        for (int s = 256; s >= 1; s >>= 1) {
            if (t < s) red[t] += red[t + s];
            __syncthreads();
        }
        if (t == 0) out[O_L] = 1.25f * red[0] * (1.0f / 4194304.0f);
    }
}

extern "C" void kernel_launch(void* const* d_in, const int* in_sizes, int n_in,
                              void* d_out, int out_size, void* d_ws, size_t ws_size,
                              hipStream_t stream) {
    const float* z_e       = (const float*)d_in[0];
    const float* cb        = (const float*)d_in[1];
    const float* ema_count = (const float*)d_in[2];
    const float* ema_sum   = (const float*)d_in[3];
    float* out             = (float*)d_out;

    float* ws_f      = (float*)d_ws;
    int*   idx_ws    = (int*)d_ws;
    float* lc_part   = ws_f + WS_LCPART;
    float* n_ws      = ws_f + WS_N;
    float* cnorm_ws  = ws_f + WS_CNORM;
    float* psum      = ws_f + WS_PSUM;
    int*   pcnt      = (int*)(ws_f + WS_PCNT);

    k_pre<<<256, 256, 0, stream>>>(cb, ema_count, cnorm_ws, n_ws);
    k_main<<<NTOT / 128, 256, 0, stream>>>(z_e, cb, cnorm_ws, out, idx_ws, lc_part);
    k_sums<<<256, 1024, 0, stream>>>(idx_ws, z_e, psum, pcnt);
    k_epi<<<64, 1024, 0, stream>>>(psum, pcnt, ema_sum, ema_count, n_ws, lc_part, out);
}

// Round 10
// 170.387 us; speedup vs baseline: 1.2646x; 1.2646x over previous
//
#include <hip/hip_runtime.h>
#include <hip/hip_bf16.h>
#include <hip/hip_fp16.h>

// Problem constants
#define NB 16
#define DD 64
#define HW 4096          // 64*64
#define NTOT 65536       // NB*HW
#define KC 1024

// Output chunk offsets (FLOAT32 elements, return order)
#define O_EK   0
#define O_IDX  4194304
#define O_L    4259840
#define O_CB   4259841
#define O_CNT  4325377
#define O_SUM  4326401

// Workspace layout (float element offsets)
#define WS_IDX    0          // [0, 65536) int32
#define WS_LCPART 65536      // 512 floats
#define WS_N      66048      // scalar
#define WS_CNORM  66560      // 1024
#define WS_PSUM   67584      // 4 x 65536 -> ends 329728
#define WS_PCNT   329728     // 4 x 1024 ints -> ends 333824
#define WS_ZN     333824     // 65536 floats -> ends 399360
#define WS_CBH    399360     // 65536 ushort = 32768 floats -> ends 432128
#define WS_CBL    432128     // 65536 ushort = 32768 floats -> ends 464896

#define MARGIN 0.002f
#define FLAGBIT 0x40000000

typedef _Float16 v8h __attribute__((ext_vector_type(8)));
typedef float    v4f __attribute__((ext_vector_type(4)));

// cnorm + n + codebook fp16 hi/lo split
__global__ __launch_bounds__(256) void k_pre(const float* __restrict__ cb,
                                             const float* __restrict__ ema_count,
                                             float* __restrict__ cnorm,
                                             float* __restrict__ n_ws,
                                             unsigned short* __restrict__ cbh,
                                             unsigned short* __restrict__ cbl) {
    const int t = threadIdx.x;
    const int w = (blockIdx.x * 256 + t) >> 6;   // code 0..1023 (grid 256)
    const int l = t & 63;
    float s = 0.f;
    if (l < 16) {
        float4 v = *(const float4*)(cb + (size_t)w * DD + l * 4);
        s = v.x * v.x + v.y * v.y + v.z * v.z + v.w * v.w;
    }
#pragma unroll
    for (int m = 1; m <= 8; m <<= 1) s += __shfl_xor(s, m, 64);
    if (l == 0) cnorm[w] = s;

    // fp16 hi/lo conversion: 16384 float4s
    const int e4 = blockIdx.x * 256 + t;
    if (e4 < 16384) {
        float4 v4 = ((const float4*)cb)[e4];
        __half hx = __float2half(v4.x), hy = __float2half(v4.y),
               hz = __float2half(v4.z), hw2 = __float2half(v4.w);
        ushort4 h4 = { __half_as_ushort(hx), __half_as_ushort(hy),
                       __half_as_ushort(hz), __half_as_ushort(hw2) };
        ((ushort4*)cbh)[e4] = h4;
        ushort4 l4 = { __half_as_ushort(__float2half(v4.x - __half2float(hx))),
                       __half_as_ushort(__float2half(v4.y - __half2float(hy))),
                       __half_as_ushort(__float2half(v4.z - __half2float(hz))),
                       __half_as_ushort(__float2half(v4.w - __half2float(hw2))) };
        ((ushort4*)cbl)[e4] = l4;
    }

    if (blockIdx.x == 0) {
        __shared__ float red[256];
        red[t] = ema_count[t] + ema_count[t + 256] + ema_count[t + 512] + ema_count[t + 768];
        __syncthreads();
        for (int s2 = 128; s2 >= 1; s2 >>= 1) {
            if (t < s2) red[t] += red[t + s2];
            __syncthreads();
        }
        if (t == 0) n_ws[0] = 0.99f * red[0] + 0.01f * 65536.0f;
    }
}

// MFMA argmin: fp16-split distance GEMM + top-2 tracking + margin flag.
// Block 256 = 4 waves; wave = 32 rows (two 16-row MFMA groups); 512 blocks.
__global__ __launch_bounds__(256) void k_argmin(const float* __restrict__ z_e,
                                                const unsigned short* __restrict__ cbh,
                                                const unsigned short* __restrict__ cbl,
                                                const float* __restrict__ cnorm,
                                                int* __restrict__ idx_ws,
                                                float* __restrict__ zn_ws) {
    __shared__ __align__(16) unsigned short Ah[128 * 72];  // z hi [m][j], pad 72
    __shared__ __align__(16) unsigned short Al[128 * 72];  // z lo
    __shared__ __align__(16) unsigned short Bh[128 * 72];  // cb hi [code][j]
    __shared__ __align__(16) unsigned short Bl[128 * 72];  // cb lo
    __shared__ __align__(16) float cn_lds[KC];

    const int t  = threadIdx.x;
    const int n0 = blockIdx.x * 128;
    const int b   = n0 >> 12;
    const int hw0 = n0 & 4095;

    *(float4*)&cn_lds[t * 4] = *(const float4*)(cnorm + t * 4);

    // ---- A staging: t<128 handles row m=t; exact fp32 zn chain alongside ----
    if (t < 128) {
        const float* zp = z_e + (size_t)b * (DD * HW) + hw0 + t;
        float s = 0.f;
        unsigned ph = 0, pl = 0;
        for (int j = 0; j < 64; ++j) {
            float v = zp[(size_t)j * HW];               // coalesced across lanes
            s = fmaf(v, v, s);                          // exact zn chain (j ascending)
            __half h = __float2half(v);
            float hf = __half2float(h);
            __half lo = __float2half(v - hf);
            unsigned uh = __half_as_ushort(h), ul = __half_as_ushort(lo);
            if ((j & 1) == 0) { ph = uh; pl = ul; }
            else {
                *(unsigned*)&Ah[t * 72 + j - 1] = ph | (uh << 16);
                *(unsigned*)&Al[t * 72 + j - 1] = pl | (ul << 16);
            }
        }
        zn_ws[n0 + t] = s;
    }
    __syncthreads();

    const int w    = t >> 6;        // wave 0..3 -> rows [32w, 32w+32)
    const int lane = t & 63;
    const int c    = lane & 15;     // col within 16-tile
    const int q    = lane >> 4;     // k-quad / row-quad

    // A fragments, loaded once: [group g][K-step s]
    v8h Afh[2][2], Afl[2][2];
#pragma unroll
    for (int g = 0; g < 2; ++g) {
        int m = 32 * w + 16 * g + c;
#pragma unroll
        for (int s = 0; s < 2; ++s) {
            Afh[g][s] = *(const v8h*)&Ah[m * 72 + s * 32 + q * 8];
            Afl[g][s] = *(const v8h*)&Al[m * 72 + s * 32 + q * 8];
        }
    }

    float m1v[2][4], m2v[2][4]; int m1i[2][4];
#pragma unroll
    for (int g = 0; g < 2; ++g)
#pragma unroll
        for (int r = 0; r < 4; ++r) { m1v[g][r] = 3.4e38f; m2v[g][r] = 3.4e38f; m1i[g][r] = 0; }

    for (int kt = 0; kt < 8; ++kt) {
        __syncthreads();
        // stage 128 codes (hi+lo) from global fp16 arrays
#pragma unroll
        for (int s2 = 0; s2 < 4; ++s2) {
            int idx = t + s2 * 256;               // 0..1023
            int code = idx >> 3;
            int off  = (idx & 7) * 8;
            size_t gsrc = ((size_t)(kt * 128 + code)) * 64 + off;
            *(uint4*)&Bh[code * 72 + off] = *(const uint4*)(cbh + gsrc);
            *(uint4*)&Bl[code * 72 + off] = *(const uint4*)(cbl + gsrc);
        }
        __syncthreads();

#pragma unroll
        for (int sub = 0; sub < 8; ++sub) {
            const int cl = sub * 16 + c;
            v8h Bfh0 = *(const v8h*)&Bh[cl * 72 + q * 8];
            v8h Bfh1 = *(const v8h*)&Bh[cl * 72 + 32 + q * 8];
            v8h Bfl0 = *(const v8h*)&Bl[cl * 72 + q * 8];
            v8h Bfl1 = *(const v8h*)&Bl[cl * 72 + 32 + q * 8];
            float cnc = cn_lds[kt * 128 + cl];
            const int kg = kt * 128 + cl;
#pragma unroll
            for (int g = 0; g < 2; ++g) {
                v4f acc = {0.f, 0.f, 0.f, 0.f};
                acc = __builtin_amdgcn_mfma_f32_16x16x32_f16(Afh[g][0], Bfh0, acc, 0, 0, 0);
                acc = __builtin_amdgcn_mfma_f32_16x16x32_f16(Afh[g][1], Bfh1, acc, 0, 0, 0);
                acc = __builtin_amdgcn_mfma_f32_16x16x32_f16(Afh[g][0], Bfl0, acc, 0, 0, 0);
                acc = __builtin_amdgcn_mfma_f32_16x16x32_f16(Afh[g][1], Bfl1, acc, 0, 0, 0);
                acc = __builtin_amdgcn_mfma_f32_16x16x32_f16(Afl[g][0], Bfh0, acc, 0, 0, 0);
                acc = __builtin_amdgcn_mfma_f32_16x16x32_f16(Afl[g][1], Bfh1, acc, 0, 0, 0);
#pragma unroll
                for (int r = 0; r < 4; ++r) {
                    float v = fmaf(-2.0f, acc[r], cnc);   // zn omitted: per-row constant
                    bool better = v < m1v[g][r];          // strict: kg ascending keeps first
                    m2v[g][r] = better ? m1v[g][r] : fminf(m2v[g][r], v);
                    m1i[g][r] = better ? kg : m1i[g][r];
                    m1v[g][r] = better ? v : m1v[g][r];
                }
            }
        }
    }

    // ---- top-2 merge across the 16 lanes (cols) holding each row ----
#pragma unroll
    for (int g = 0; g < 2; ++g)
#pragma unroll
        for (int r = 0; r < 4; ++r) {
            float a = m1v[g][r], b2 = m2v[g][r]; int ii = m1i[g][r];
#pragma unroll
            for (int mask = 1; mask <= 8; mask <<= 1) {
                float ov = __shfl_xor(a, mask, 64);
                int   oi = __shfl_xor(ii, mask, 64);
                float o2 = __shfl_xor(b2, mask, 64);
                bool take = (ov < a) || (ov == a && oi < ii);
                float loser = take ? a : ov;
                b2 = fminf(fminf(b2, o2), loser);
                a  = take ? ov : a;
                ii = take ? oi : ii;
            }
            if (c == 0) {
                int row = 32 * w + 16 * g + q * 4 + r;
                int enc = ((b2 - a) < MARGIN) ? (ii | FLAGBIT) : ii;
                idx_ws[n0 + row] = enc;
            }
        }
}

// Fix flagged rows (exact fp32, np-matching) + e_k_ste + idx out + L_commit partial.
__global__ __launch_bounds__(256) void k_scatter(const float* __restrict__ z_e,
                                                 const float* __restrict__ cb,
                                                 const float* __restrict__ cnorm,
                                                 const float* __restrict__ zn_ws,
                                                 int* __restrict__ idx_ws,
                                                 float* __restrict__ out,
                                                 float* __restrict__ lc_part) {
    __shared__ int idx_lds[128];
    __shared__ int flagrows[128];
    __shared__ int nflag;
    __shared__ float redv[256];
    __shared__ int   redi[256];
    __shared__ float lcred[4];

    const int t  = threadIdx.x;
    const int n0 = blockIdx.x * 128;
    const int b   = n0 >> 12;
    const int hw0 = n0 & 4095;

    if (t == 0) nflag = 0;
    __syncthreads();
    if (t < 128) {
        int raw = idx_ws[n0 + t];
        idx_lds[t] = raw & 1023;
        if (raw & FLAGBIT) { int p = atomicAdd(&nflag, 1); flagrows[p] = t; }
    }
    __syncthreads();
    const int nf = nflag;
    for (int f = 0; f < nf; ++f) {
        int row = flagrows[f];
        int n = n0 + row;
        const float* zp = z_e + (size_t)b * (DD * HW) + (hw0 + row);
        float znr = zn_ws[n];
        float best = 3.4e38f; int bi = 0;
#pragma unroll
        for (int c2 = 0; c2 < 4; ++c2) {
            int k = t * 4 + c2;                      // ascending within thread
            const float* ck = cb + (size_t)k * DD;
            float acc = 0.f;
            for (int j = 0; j < 64; ++j) acc = fmaf(zp[(size_t)j * HW], ck[j], acc);
            float v = (znr - 2.0f * acc) + cnorm[k]; // same expression as passing fp32 kernel
            if (v < best) { best = v; bi = k; }
        }
        redv[t] = best; redi[t] = bi;
        __syncthreads();
        for (int s = 128; s >= 1; s >>= 1) {
            if (t < s) {
                float v = redv[t + s]; int i = redi[t + s];
                if (v < redv[t] || (v == redv[t] && i < redi[t])) { redv[t] = v; redi[t] = i; }
            }
            __syncthreads();
        }
        if (t == 0) { idx_lds[row] = redi[0]; idx_ws[n] = redi[0]; }
        __syncthreads();
    }

    if (t < 128) out[O_IDX + n0 + t] = (float)idx_lds[t];

    // e_k_ste + L_commit (z from global; L3-warm from k_argmin)
    const int r  = t >> 1;
    const int j0 = (t & 1) * 32;
    int k = idx_lds[r];
    const float* ck = cb + (size_t)k * DD;
    const float* zb = z_e + (size_t)b * (DD * HW) + (hw0 + r);
    const size_t obase = (size_t)b * (DD * HW) + (size_t)(hw0 + r);

    float lc = 0.f;
#pragma unroll 8
    for (int j = j0; j < j0 + 32; ++j) {
        float z = zb[(size_t)j * HW];
        float e = ck[j];
        out[O_EK + obase + (size_t)j * HW] = z + (e - z);
        float d = z - e;
        lc = fmaf(d, d, lc);
    }
#pragma unroll
    for (int m = 32; m >= 1; m >>= 1) lc += __shfl_xor(lc, m, 64);
    if ((t & 63) == 0) lcred[t >> 6] = lc;
    __syncthreads();
    if (t == 0) lc_part[blockIdx.x] = lcred[0] + lcred[1] + lcred[2] + lcred[3];
}

// 256 blocks: (j, chunk c). Vectorized loads; LDS accumulate; j==0 also histograms.
__global__ __launch_bounds__(1024) void k_sums(const int* __restrict__ idx_ws,
                                               const float* __restrict__ z_e,
                                               float* __restrict__ psum,
                                               int* __restrict__ pcnt) {
    __shared__ float acc[KC];
    __shared__ int bins[KC];
    const int j = blockIdx.x & 63;
    const int c = blockIdx.x >> 6;
    const int t = threadIdx.x;
    acc[t] = 0.f;
    bins[t] = 0;
    __syncthreads();
    const float* zj = z_e + (size_t)j * HW;
    const int base = c * 16384;
    if (j == 0) {
#pragma unroll
        for (int i = 0; i < 4; ++i) {
            int n4 = base + i * 4096 + t * 4;
            int b = n4 >> 12, hw = n4 & 4095;
            float4 z4 = *(const float4*)(zj + (size_t)b * (DD * HW) + hw);
            int4   k4 = *(const int4*)(idx_ws + n4);
            atomicAdd(&acc[k4.x], z4.x); atomicAdd(&bins[k4.x], 1);
            atomicAdd(&acc[k4.y], z4.y); atomicAdd(&bins[k4.y], 1);
            atomicAdd(&acc[k4.z], z4.z); atomicAdd(&bins[k4.z], 1);
            atomicAdd(&acc[k4.w], z4.w); atomicAdd(&bins[k4.w], 1);
        }
    } else {
#pragma unroll
        for (int i = 0; i < 4; ++i) {
            int n4 = base + i * 4096 + t * 4;
            int b = n4 >> 12, hw = n4 & 4095;
            float4 z4 = *(const float4*)(zj + (size_t)b * (DD * HW) + hw);
            int4   k4 = *(const int4*)(idx_ws + n4);
            atomicAdd(&acc[k4.x], z4.x);
            atomicAdd(&acc[k4.y], z4.y);
            atomicAdd(&acc[k4.z], z4.z);
            atomicAdd(&acc[k4.w], z4.w);
        }
    }
    __syncthreads();
    psum[(size_t)c * 65536 + j * 1024 + t] = acc[t];
    if (j == 0) pcnt[c * 1024 + t] = bins[t];
}

// Fused epilogue, coalesced on outputs: e = k*64+j. 64 blocks x 1024.
__global__ __launch_bounds__(1024) void k_epi(const float* __restrict__ psum,
                                              const int* __restrict__ pcnt,
                                              const float* __restrict__ ema_sum,
                                              const float* __restrict__ ema_count,
                                              const float* __restrict__ n_ws,
                                              const float* __restrict__ lc_part,
                                              float* __restrict__ out) {
    const int t = threadIdx.x;
    const int e = blockIdx.x * 1024 + t;
    const int k = e >> 6, j = e & 63;
    float s4 = psum[j * 1024 + k] + psum[65536 + j * 1024 + k]
             + psum[131072 + j * 1024 + k] + psum[196608 + j * 1024 + k];
    float ns = ema_sum[e] * 0.99f + 0.01f * s4;
    out[O_SUM + e] = ns;
    int cnt = pcnt[k] + pcnt[1024 + k] + pcnt[2048 + k] + pcnt[3072 + k];
    float nc = ema_count[k] * 0.99f + 0.01f * (float)cnt;
    float n  = n_ws[0];
    float cs = (nc + 1e-5f) / (n + 1024.0f * 1e-5f) * n;
    out[O_CB + e] = ns / cs;
    if (blockIdx.x == 0) {
        int c2 = pcnt[t] + pcnt[1024 + t] + pcnt[2048 + t] + pcnt[3072 + t];
        out[O_CNT + t] = ema_count[t] * 0.99f + 0.01f * (float)c2;
    }
    if (blockIdx.x == 1) {
        __shared__ float red[512];
        if (t < 512) red[t] = lc_part[t];
        __syncthreads();
        for (int s = 256; s >= 1; s >>= 1) {
            if (t < s) red[t] += red[t + s];
            __syncthreads();
        }
        if (t == 0) out[O_L] = 1.25f * red[0] * (1.0f / 4194304.0f);
    }
}

extern "C" void kernel_launch(void* const* d_in, const int* in_sizes, int n_in,
                              void* d_out, int out_size, void* d_ws, size_t ws_size,
                              hipStream_t stream) {
    const float* z_e       = (const float*)d_in[0];
    const float* cb        = (const float*)d_in[1];
    const float* ema_count = (const float*)d_in[2];
    const float* ema_sum   = (const float*)d_in[3];
    float* out             = (float*)d_out;

    float* ws_f      = (float*)d_ws;
    int*   idx_ws    = (int*)d_ws;
    float* lc_part   = ws_f + WS_LCPART;
    float* n_ws      = ws_f + WS_N;
    float* cnorm_ws  = ws_f + WS_CNORM;
    float* psum      = ws_f + WS_PSUM;
    int*   pcnt      = (int*)(ws_f + WS_PCNT);
    float* zn_ws     = ws_f + WS_ZN;
    unsigned short* cbh = (unsigned short*)(ws_f + WS_CBH);
    unsigned short* cbl = (unsigned short*)(ws_f + WS_CBL);

    k_pre<<<256, 256, 0, stream>>>(cb, ema_count, cnorm_ws, n_ws, cbh, cbl);
    k_argmin<<<NTOT / 128, 256, 0, stream>>>(z_e, cbh, cbl, cnorm_ws, idx_ws, zn_ws);
    k_scatter<<<NTOT / 128, 256, 0, stream>>>(z_e, cb, cnorm_ws, zn_ws, idx_ws, out, lc_part);
    k_sums<<<256, 1024, 0, stream>>>(idx_ws, z_e, psum, pcnt);
    k_epi<<<64, 1024, 0, stream>>>(psum, pcnt, ema_sum, ema_count, n_ws, lc_part, out);
}